// Round 7
// baseline (366.560 us; speedup 1.0000x reference)
//
#include <hip/hip_runtime.h>
#include <cstdint>
#include <cmath>

// LQE split: (A) q-compute, 2 waves/block each owning a private LDS subtile,
// no block barriers in the tile path; (B) streaming add with LDS q-broadcast.
// B=32, L=10000 -> 320000 anchors; 4 sides x 33 bins; k_top=4; HID=64; NC=80.
//
// R10 == R9 resubmitted verbatim (R9 hit an infra failure: "container
// failed twice" -- no compile/correctness signal; theory unmeasured).
//
// R9 theory: R8's lqe_q (~83us ~= 2 TB/s) matched the pre-registered
// failure tell: 38.4KB/block -> 4 single-wave blocks/CU = 1 wave/SIMD, so
// a staging wave leaves its SIMD idle; avg in-flight ~13KB < the ~22KB
// Little's-law need for the 24.6 GB/s/CU HBM share. Concurrency, not
// coalescing, was the deficit. Now: 128-thread blocks = 2 waves, each with
// a PRIVATE 33.8KB subtile (hand-off is cross-lane within one wave only),
// 72KB/block -> 2 blocks/CU = 8 waves/CU, 2/SIMD. Tile path uses the
// R5-proven within-wave fence (s_waitcnt lgkmcnt(0) + memory clobber +
// sched_barrier(0), rule #18) instead of __syncthreads, so waves drift
// and one wave's compute hides the other's stage. Global side stays fully
// coalesced (lane i <- base+i*16B); anchor stride 132 floats == 4 mod 32
// banks -> ds_write/ds_read both at the wave64-b128 minimum, NO padding.
// lqe_add: q gather (64 addrs/wave) replaced by LDS broadcast.

constexpr int NB   = 33;
constexpr int F4PA = 33;    // float4 per anchor
constexpr int HID  = 64;
constexpr int NCLS = 80;
constexpr int APT  = 64;    // anchors per wave-subtile == lanes

// ---- kernel A: pred -> per-anchor quality q ----
__global__ __attribute__((amdgpu_flat_work_group_size(128, 128)))
void lqe_q(
    const float* __restrict__ pred,
    const float* __restrict__ w1,
    const float* __restrict__ b1,
    const float* __restrict__ w2,
    const float* __restrict__ b2,
    float* __restrict__ qout)
{
    __shared__ float4 s_buf[2][APT * F4PA];  // 2 x 33792 B, wave-private
    __shared__ float  s_w1[HID * 16];        // folded: w1[j][5s+q]+.25*w1[j][5s+4]
    __shared__ float  s_b1[HID];
    __shared__ float  s_w2[HID];

    const int t = threadIdx.x;               // 0..127

    // ---- fold weights: threads 0..63, row t each ----
    if (t < HID) {
        float wr[20];
        const float4* ws = (const float4*)(w1 + t * 20);   // 80B: 16B-aligned
        #pragma unroll
        for (int i = 0; i < 5; ++i) ((float4*)wr)[i] = ws[i];
        #pragma unroll
        for (int s = 0; s < 4; ++s) {
            float wm = 0.25f * wr[s * 5 + 4];
            #pragma unroll
            for (int q = 0; q < 4; ++q)
                s_w1[t * 16 + s * 4 + q] = wr[s * 5 + q] + wm;
        }
        s_b1[t] = b1[t];
        s_w2[t] = w2[t];
    }
    const float b2r = b2[0];
    __syncthreads();                         // weights visible to both waves

    const int w = t >> 6;                    // wave id 0/1
    const int l = t & 63;                    // lane
    const long long tile = (long long)blockIdx.x * 2 + w;
    const float4* g4 = (const float4*)pred + tile * (APT * F4PA);
    float4* sb = &s_buf[w][0];

    // ---- stage: 33 coalesced float4 (identity layout: linear idx =
    //      anchor*33+col), 8-deep reg batches; wave-private buffer ----
    #pragma unroll
    for (int g = 0; g < 4; ++g) {
        float4 r[8];
        #pragma unroll
        for (int j = 0; j < 8; ++j) r[j] = g4[(g * 8 + j) * 64 + l];
        #pragma unroll
        for (int j = 0; j < 8; ++j) sb[(g * 8 + j) * 64 + l] = r[j];
    }
    { float4 r = g4[32 * 64 + l]; sb[32 * 64 + l] = r; }

    // within-wave fence (R5-proven): order ds_write -> ds_read for the
    // compiler ("memory" clobber) and drain the LDS queue; sched_barrier
    // pins any hoisting past the asm (rule #18).
    asm volatile("s_waitcnt lgkmcnt(0)" ::: "memory");
    __builtin_amdgcn_sched_barrier(0);

    // ---- compute: softmax-top4 stats from this lane's anchor row ----
    const float4* lp = sb + l * F4PA;        // 528 B stride, conflict-minimal
    float f[16];
    float e0 = 0.f, e1 = 0.f, e2 = 0.f, e3 = 0.f, sum = 0.f;
    #pragma unroll
    for (int ld = 0; ld < 33; ++ld) {
        float4 v4 = lp[ld];
        float vv[4] = {v4.x, v4.y, v4.z, v4.w};
        #pragma unroll
        for (int c = 0; c < 4; ++c) {
            const int idx = 4 * ld + c;            // compile-time
            float e = __expf(vv[c]);
            sum += e;
            // branchless top-4 insertion (exp >= 0, so 0-init == -inf)
            float n0 = fminf(e0, e);  e0 = fmaxf(e0, e);
            float n1 = fminf(e1, n0); e1 = fmaxf(e1, n0);
            float n2 = fminf(e2, n1); e2 = fmaxf(e2, n1);
            e3 = fmaxf(e3, n2);
            if (idx % NB == NB - 1) {              // side done: 32/65/98/131
                const int s = idx / NB;
                float inv = 1.0f / sum;
                f[s * 4 + 0] = e0 * inv;
                f[s * 4 + 1] = e1 * inv;
                f[s * 4 + 2] = e2 * inv;
                f[s * 4 + 3] = e3 * inv;
                e0 = e1 = e2 = e3 = 0.f; sum = 0.f;
            }
        }
    }

    // ---- MLP: h_j = relu(b1_j + f . w1eff_j); qv = b2 + h . w2 ----
    float qv = b2r;
    #pragma unroll
    for (int j = 0; j < HID; ++j) {
        const float4* wr = (const float4*)(s_w1 + j * 16);  // uniform bcast
        float hj = s_b1[j];
        #pragma unroll
        for (int i4 = 0; i4 < 4; ++i4) {
            float4 wv = wr[i4];
            hj = fmaf(f[4 * i4 + 0], wv.x, hj);
            hj = fmaf(f[4 * i4 + 1], wv.y, hj);
            hj = fmaf(f[4 * i4 + 2], wv.z, hj);
            hj = fmaf(f[4 * i4 + 3], wv.w, hj);
        }
        hj = fmaxf(hj, 0.f);
        qv = fmaf(hj, s_w2[j], qv);
    }
    qout[tile * APT + l] = qv;               // coalesced 256B store per wave
}

// ---- kernel B: out = scores + q; q via LDS broadcast, pure streaming ----
__global__ __launch_bounds__(256)
void lqe_add(
    const float* __restrict__ scores,
    const float* __restrict__ qin,
    float* __restrict__ out)
{
    __shared__ float s_q[64];
    const int t = threadIdx.x;
    const long long a0 = (long long)blockIdx.x * 64;   // 64 anchors per block

    if (t < 64) s_q[t] = qin[a0 + t];
    __syncthreads();

    const float4* sc4 = (const float4*)(scores + a0 * NCLS);
    float4*       ot4 = (float4*)(out + a0 * NCLS);

    float4 v[5];
    float  q[5];
    #pragma unroll
    for (int u = 0; u < 5; ++u) {            // 5*256 = 1280 float4 per block
        const int i = u * 256 + t;
        v[u] = sc4[i];                       // coalesced 1KB per wave-instr
        q[u] = s_q[i / 20];                  // LDS broadcast (20 lanes/addr)
    }
    #pragma unroll
    for (int u = 0; u < 5; ++u) {
        const int i = u * 256 + t;
        float4 x = v[u];
        float qq = q[u];
        x.x += qq; x.y += qq; x.z += qq; x.w += qq;
        ot4[i] = x;
    }
}

extern "C" void kernel_launch(void* const* d_in, const int* in_sizes, int n_in,
                              void* d_out, int out_size, void* d_ws, size_t ws_size,
                              hipStream_t stream) {
    const float* scores = (const float*)d_in[0];
    const float* pred   = (const float*)d_in[1];
    const float* w1     = (const float*)d_in[2];
    const float* b1     = (const float*)d_in[3];
    const float* w2     = (const float*)d_in[4];
    const float* b2     = (const float*)d_in[5];
    // d_in[6] = k_top (==4, baked in)

    int n_anchor = in_sizes[0] / NCLS;       // 320000
    float* qbuf  = (float*)d_ws;             // 1.28 MB scratch

    lqe_q<<<n_anchor / 128, 128, 0, stream>>>(pred, w1, b1, w2, b2, qbuf);

    lqe_add<<<n_anchor / 64, 256, 0, stream>>>(scores, qbuf, (float*)d_out);
}